// Round 1
// baseline (193.056 us; speedup 1.0000x reference)
//
#include <hip/hip_runtime.h>

// Problem: N=2048, M=512, D=128, all fp32.
// Outputs (flat concat): [0]=min_loss (scalar), [1]=wise_min_loss (scalar),
//                        [2..2+N*D)=z_out.
// ws layout (unsigned bits of nonneg floats, so unsigned compare == float compare):
//   ws[0..M)        : min_sum[m]
//   ws[M..M+M*D)    : min_elem[m*D+d]

#define N_ 2048
#define M_ 512
#define D_ 128
#define WS_TOTAL (M_ + M_ * D_)   // 66048 uints = 264KB

__global__ void k_init(unsigned int* __restrict__ ws) {
    int i = blockIdx.x * 256 + threadIdx.x;
    if (i < WS_TOTAL) ws[i] = 0x7f800000u;  // +inf bits
}

// min_elem: grid(64, 8), block 256.
// blockIdx.x = m-group (8 m's), blockIdx.y = n-chunk (256 n's).
// thread t: d = t&127, half = t>>7 -> 4 m's per thread, min in registers.
__global__ void __launch_bounds__(256) k_minelem(
        const float* __restrict__ z, const float* __restrict__ e,
        unsigned int* __restrict__ ws) {
    const int t = threadIdx.x;
    const int d = t & 127;
    const int half = t >> 7;
    const int m0 = blockIdx.x * 8 + half * 4;
    const int n0 = blockIdx.y * 256;

    const float e0 = e[(m0 + 0) * D_ + d];
    const float e1 = e[(m0 + 1) * D_ + d];
    const float e2 = e[(m0 + 2) * D_ + d];
    const float e3 = e[(m0 + 3) * D_ + d];

    float me0 = __uint_as_float(0x7f800000u), me1 = me0, me2 = me0, me3 = me0;

    const float* zp = z + n0 * D_ + d;
    #pragma unroll 8
    for (int i = 0; i < 256; ++i) {
        float zv = zp[i * D_];
        float df;
        df = zv - e0; me0 = fminf(me0, df * df);
        df = zv - e1; me1 = fminf(me1, df * df);
        df = zv - e2; me2 = fminf(me2, df * df);
        df = zv - e3; me3 = fminf(me3, df * df);
    }
    unsigned int* me = ws + M_;
    atomicMin(&me[(m0 + 0) * D_ + d], __float_as_uint(me0));
    atomicMin(&me[(m0 + 1) * D_ + d], __float_as_uint(me1));
    atomicMin(&me[(m0 + 2) * D_ + d], __float_as_uint(me2));
    atomicMin(&me[(m0 + 3) * D_ + d], __float_as_uint(me3));
}

// min_sum: grid(8, 32), block 256. Thread owns n = bx*256+t; z row in VGPRs.
// blockIdx.y selects a chunk of 16 m's. e accessed wave-uniformly.
__global__ void __launch_bounds__(256, 1) k_minsum(
        const float* __restrict__ z, const float* __restrict__ e,
        unsigned int* __restrict__ ws) {
    const int t = threadIdx.x;
    const int n = blockIdx.x * 256 + t;
    const int m0 = blockIdx.y * 16;

    // Load z[n][0..127] into registers (32 x float4, fully unrolled).
    float4 zr[32];
    const float4* z4 = reinterpret_cast<const float4*>(z) + n * 32;
    #pragma unroll
    for (int j = 0; j < 32; ++j) zr[j] = z4[j];

    const float4* e4 = reinterpret_cast<const float4*>(e);
    for (int mi = 0; mi < 16; ++mi) {
        const int m = m0 + mi;
        float s0 = 0.f, s1 = 0.f, s2 = 0.f, s3 = 0.f;
        #pragma unroll
        for (int j = 0; j < 32; ++j) {
            float4 ev = e4[m * 32 + j];     // wave-uniform address
            float dx = zr[j].x - ev.x; s0 = fmaf(dx, dx, s0);
            float dy = zr[j].y - ev.y; s1 = fmaf(dy, dy, s1);
            float dz = zr[j].z - ev.z; s2 = fmaf(dz, dz, s2);
            float dw = zr[j].w - ev.w; s3 = fmaf(dw, dw, s3);
        }
        float dsum = (s0 + s1) + (s2 + s3);
        // wave-64 min reduce
        #pragma unroll
        for (int off = 32; off; off >>= 1)
            dsum = fminf(dsum, __shfl_xor(dsum, off));
        if ((t & 63) == 0)
            atomicMin(&ws[m], __float_as_uint(dsum));
    }
}

// Finalize: 1 block, 256 threads. out[0]=mean(min_sum), out[1]=mean(min_elem).
__global__ void k_finalize(const unsigned int* __restrict__ ws,
                           float* __restrict__ out) {
    __shared__ float sm[16];
    const int t = threadIdx.x;
    float s1 = __uint_as_float(ws[t]) + __uint_as_float(ws[t + 256]);
    float s2 = 0.f;
    const unsigned int* me = ws + M_;
    for (int i = t; i < M_ * D_; i += 256) s2 += __uint_as_float(me[i]);
    #pragma unroll
    for (int off = 32; off; off >>= 1) {
        s1 += __shfl_xor(s1, off);
        s2 += __shfl_xor(s2, off);
    }
    const int w = t >> 6;
    if ((t & 63) == 0) { sm[w] = s1; sm[8 + w] = s2; }
    __syncthreads();
    if (t == 0) {
        float a = sm[0] + sm[1] + sm[2] + sm[3];
        float b = sm[8] + sm[9] + sm[10] + sm[11];
        out[0] = a * (1.0f / 512.0f);
        out[1] = b * (1.0f / 65536.0f);
    }
}

// z_out = z * (dropout < probs[n]); out+2 is only 8B-aligned -> float2 stores.
__global__ void k_mask(const float* __restrict__ z, const float* __restrict__ probs,
                       const float* __restrict__ drop, float* __restrict__ out) {
    const int i = blockIdx.x * 256 + threadIdx.x;   // float4 index, 65536 total
    const int n = i >> 5;                           // (i*4)/128
    const float p = probs[n];
    const float4 zv = reinterpret_cast<const float4*>(z)[i];
    const float4 dv = reinterpret_cast<const float4*>(drop)[i];
    float2 lo, hi;
    lo.x = dv.x < p ? zv.x : 0.f;
    lo.y = dv.y < p ? zv.y : 0.f;
    hi.x = dv.z < p ? zv.z : 0.f;
    hi.y = dv.w < p ? zv.w : 0.f;
    float2* o = reinterpret_cast<float2*>(out + 2) + i * 2;
    o[0] = lo;
    o[1] = hi;
}

extern "C" void kernel_launch(void* const* d_in, const int* in_sizes, int n_in,
                              void* d_out, int out_size, void* d_ws, size_t ws_size,
                              hipStream_t stream) {
    const float* z     = (const float*)d_in[0];
    const float* e     = (const float*)d_in[1];
    const float* probs = (const float*)d_in[2];
    const float* drop  = (const float*)d_in[3];
    float* out = (float*)d_out;
    unsigned int* ws = (unsigned int*)d_ws;

    k_init<<<dim3((WS_TOTAL + 255) / 256), dim3(256), 0, stream>>>(ws);
    k_mask<<<dim3((N_ * D_ / 4) / 256), dim3(256), 0, stream>>>(z, probs, drop, out);
    k_minelem<<<dim3(M_ / 8, N_ / 256), dim3(256), 0, stream>>>(z, e, ws);
    k_minsum<<<dim3(N_ / 256, M_ / 16), dim3(256), 0, stream>>>(z, e, ws);
    k_finalize<<<dim3(1), dim3(256), 0, stream>>>(ws, out);
}

// Round 2
// 122.791 us; speedup vs baseline: 1.5722x; 1.5722x over previous
//
#include <hip/hip_runtime.h>

// Problem: N=2048, M=512, D=128, all fp32.
// Outputs (flat concat): [0]=min_loss (scalar), [1]=wise_min_loss (scalar),
//                        [2..2+N*D)=z_out.
// ws layout (unsigned bits of nonneg floats; unsigned compare == float compare):
//   ws[0..M)            : min_sum[m]
//   ws[M..M+M*D)        : min_elem[m*D+d]
//   ws[WS_TOTAL..+2)    : float accumulators (sum of min_sum, sum of min_elem)

#define N_ 2048
#define M_ 512
#define D_ 128
#define WS_TOTAL (M_ + M_ * D_)   // 66048 uints = 264KB

__global__ void k_init(unsigned int* __restrict__ ws) {
    int i = blockIdx.x * 256 + threadIdx.x;
    if (i < WS_TOTAL) ws[i] = 0x7f800000u;  // +inf bits
    else if (i < WS_TOTAL + 2) ws[i] = 0u;  // accumulators = 0.0f
}

// min_elem: grid(64, 8), block 256.
// blockIdx.x = m-group (8 m's), blockIdx.y = n-chunk (256 n's).
// thread t: d = t&127, half = t>>7 -> 4 m's per thread, min in registers.
__global__ void __launch_bounds__(256) k_minelem(
        const float* __restrict__ z, const float* __restrict__ e,
        unsigned int* __restrict__ ws) {
    const int t = threadIdx.x;
    const int d = t & 127;
    const int half = t >> 7;
    const int m0 = blockIdx.x * 8 + half * 4;
    const int n0 = blockIdx.y * 256;

    const float e0 = e[(m0 + 0) * D_ + d];
    const float e1 = e[(m0 + 1) * D_ + d];
    const float e2 = e[(m0 + 2) * D_ + d];
    const float e3 = e[(m0 + 3) * D_ + d];

    float me0 = __uint_as_float(0x7f800000u), me1 = me0, me2 = me0, me3 = me0;

    const float* zp = z + n0 * D_ + d;
    #pragma unroll 8
    for (int i = 0; i < 256; ++i) {
        float zv = zp[i * D_];
        float df;
        df = zv - e0; me0 = fminf(me0, df * df);
        df = zv - e1; me1 = fminf(me1, df * df);
        df = zv - e2; me2 = fminf(me2, df * df);
        df = zv - e3; me3 = fminf(me3, df * df);
    }
    unsigned int* me = ws + M_;
    atomicMin(&me[(m0 + 0) * D_ + d], __float_as_uint(me0));
    atomicMin(&me[(m0 + 1) * D_ + d], __float_as_uint(me1));
    atomicMin(&me[(m0 + 2) * D_ + d], __float_as_uint(me2));
    atomicMin(&me[(m0 + 3) * D_ + d], __float_as_uint(me3));
}

// min_sum: grid(8, 32), block 256. Thread owns n = bx*256+t; z row in VGPRs.
// blockIdx.y selects a chunk of 16 m's (processed 2 at a time for ILP).
// e accessed wave-uniformly (scalarizable).
__global__ void __launch_bounds__(256, 1) k_minsum(
        const float* __restrict__ z, const float* __restrict__ e,
        unsigned int* __restrict__ ws) {
    const int t = threadIdx.x;
    const int n = blockIdx.x * 256 + t;
    const int m0 = blockIdx.y * 16;

    // Load z[n][0..127] into registers (32 x float4, fully unrolled).
    float4 zr[32];
    const float4* z4 = reinterpret_cast<const float4*>(z) + n * 32;
    #pragma unroll
    for (int j = 0; j < 32; ++j) zr[j] = z4[j];

    const float4* e4 = reinterpret_cast<const float4*>(e);
    for (int mi = 0; mi < 16; mi += 2) {
        const int ma = m0 + mi;
        const int mb = ma + 1;
        float a0 = 0.f, a1 = 0.f, a2 = 0.f, a3 = 0.f;
        float b0 = 0.f, b1 = 0.f, b2 = 0.f, b3 = 0.f;
        #pragma unroll
        for (int j = 0; j < 32; ++j) {
            float4 ea = e4[ma * 32 + j];    // wave-uniform address
            float4 eb = e4[mb * 32 + j];
            float dx, dy, dz, dw;
            dx = zr[j].x - ea.x; a0 = fmaf(dx, dx, a0);
            dy = zr[j].y - ea.y; a1 = fmaf(dy, dy, a1);
            dz = zr[j].z - ea.z; a2 = fmaf(dz, dz, a2);
            dw = zr[j].w - ea.w; a3 = fmaf(dw, dw, a3);
            dx = zr[j].x - eb.x; b0 = fmaf(dx, dx, b0);
            dy = zr[j].y - eb.y; b1 = fmaf(dy, dy, b1);
            dz = zr[j].z - eb.z; b2 = fmaf(dz, dz, b2);
            dw = zr[j].w - eb.w; b3 = fmaf(dw, dw, b3);
        }
        float sa = (a0 + a1) + (a2 + a3);
        float sb = (b0 + b1) + (b2 + b3);
        #pragma unroll
        for (int off = 32; off; off >>= 1) {
            sa = fminf(sa, __shfl_xor(sa, off));
            sb = fminf(sb, __shfl_xor(sb, off));
        }
        if ((t & 63) == 0) {
            atomicMin(&ws[ma], __float_as_uint(sa));
            atomicMin(&ws[mb], __float_as_uint(sb));
        }
    }
}

// Parallel reduce: grid 64 blocks x 256 threads. Each thread sums one float4 of
// min_elem; block 0's first 128 threads also cover min_sum. Wave-reduce, then
// atomicAdd into ws accumulators.
__global__ void k_reduce(const unsigned int* __restrict__ ws_u,
                         float* __restrict__ acc) {
    const int t = threadIdx.x;
    const int i = blockIdx.x * 256 + t;     // float4 index into min_elem (16384)
    const float* ws_f = reinterpret_cast<const float*>(ws_u);
    const float4* me4 = reinterpret_cast<const float4*>(ws_f + M_);
    float4 v = me4[i];
    float s_elem = (v.x + v.y) + (v.z + v.w);
    float s_sum = 0.f;
    if (blockIdx.x == 0 && t < 128) {
        float4 u = reinterpret_cast<const float4*>(ws_f)[t];
        s_sum = (u.x + u.y) + (u.z + u.w);
    }
    #pragma unroll
    for (int off = 32; off; off >>= 1) {
        s_elem += __shfl_xor(s_elem, off);
        s_sum  += __shfl_xor(s_sum, off);
    }
    if ((t & 63) == 0) {
        atomicAdd(&acc[0], s_sum);
        atomicAdd(&acc[1], s_elem);
    }
}

__global__ void k_final(const float* __restrict__ acc, float* __restrict__ out) {
    if (threadIdx.x == 0) {
        out[0] = acc[0] * (1.0f / 512.0f);
        out[1] = acc[1] * (1.0f / 65536.0f);
    }
}

// z_out = z * (dropout < probs[n]); out+2 is only 8B-aligned -> float2 stores.
__global__ void k_mask(const float* __restrict__ z, const float* __restrict__ probs,
                       const float* __restrict__ drop, float* __restrict__ out) {
    const int i = blockIdx.x * 256 + threadIdx.x;   // float4 index, 65536 total
    const int n = i >> 5;                           // (i*4)/128
    const float p = probs[n];
    const float4 zv = reinterpret_cast<const float4*>(z)[i];
    const float4 dv = reinterpret_cast<const float4*>(drop)[i];
    float2 lo, hi;
    lo.x = dv.x < p ? zv.x : 0.f;
    lo.y = dv.y < p ? zv.y : 0.f;
    hi.x = dv.z < p ? zv.z : 0.f;
    hi.y = dv.w < p ? zv.w : 0.f;
    float2* o = reinterpret_cast<float2*>(out + 2) + i * 2;
    o[0] = lo;
    o[1] = hi;
}

extern "C" void kernel_launch(void* const* d_in, const int* in_sizes, int n_in,
                              void* d_out, int out_size, void* d_ws, size_t ws_size,
                              hipStream_t stream) {
    const float* z     = (const float*)d_in[0];
    const float* e     = (const float*)d_in[1];
    const float* probs = (const float*)d_in[2];
    const float* drop  = (const float*)d_in[3];
    float* out = (float*)d_out;
    unsigned int* ws = (unsigned int*)d_ws;
    float* acc = reinterpret_cast<float*>(ws + WS_TOTAL);

    k_init<<<dim3((WS_TOTAL + 2 + 255) / 256), dim3(256), 0, stream>>>(ws);
    k_mask<<<dim3((N_ * D_ / 4) / 256), dim3(256), 0, stream>>>(z, probs, drop, out);
    k_minelem<<<dim3(M_ / 8, N_ / 256), dim3(256), 0, stream>>>(z, e, ws);
    k_minsum<<<dim3(N_ / 256, M_ / 16), dim3(256), 0, stream>>>(z, e, ws);
    k_reduce<<<dim3(64), dim3(256), 0, stream>>>(ws, acc);
    k_final<<<dim3(1), dim3(64), 0, stream>>>(acc, out);
}

// Round 3
// 87.496 us; speedup vs baseline: 2.2065x; 1.4034x over previous
//
#include <hip/hip_runtime.h>

// Problem: N=2048, M=512, D=128, all fp32.
// Outputs (flat): [0]=min_loss, [1]=wise_min_loss, [2..2+N*D)=z_out.
//
// Structure: 2 dispatches.
//  k_main (1024 blocks, heterogeneous):
//    bx in [0,512)   : elem partials. block=(m-group of 8, n-chunk of 256);
//                      thread owns (d, 4 m's); min over chunk in regs; plain store.
//    bx in [512,768) : sum partials. block=(n-block of 256, m-tile of 16);
//                      z row in VGPRs; per-wave min per m; plain store.
//    bx in [768,1024): dropout mask; block 768 also zeroes acc/counter.
//  k_fin (64 blocks): min over 8 chunks + sum (elem), min over 32 partials +
//    sum (sum path), atomicAdd into acc, last-block writes out[0..1].
//
// ws layout (floats):
//   [0 .. 524288)        pb_elem[chunk][m][d]   (8*512*128, 2MB)
//   [524288 .. 540672)   pb_sum[m][32]          (512*32)
//   [540672 .. +2)       acc[2]
//   [540674]             counter (uint)

#define N_ 2048
#define M_ 512
#define D_ 128
#define PB_SUM  (8 * M_ * D_)          // 524288
#define ACC_OFF (PB_SUM + M_ * 32)     // 540672
#define CNT_OFF (ACC_OFF + 2)

__global__ void __launch_bounds__(256, 2) k_main(
        const float* __restrict__ z, const float* __restrict__ e,
        const float* __restrict__ probs, const float* __restrict__ drop,
        float* __restrict__ out, float* __restrict__ ws) {
    const int bx = blockIdx.x;
    const int t  = threadIdx.x;

    if (bx < 512) {
        // ---- elem partials: min over one 256-n chunk for 8 m's ----
        const int mg = bx >> 3, chunk = bx & 7;
        const int d = t & 127, half = t >> 7;
        const int m0 = mg * 8 + half * 4;
        const int n0 = chunk * 256;

        const float e0 = e[(m0 + 0) * D_ + d];
        const float e1 = e[(m0 + 1) * D_ + d];
        const float e2 = e[(m0 + 2) * D_ + d];
        const float e3 = e[(m0 + 3) * D_ + d];

        float me0 = __uint_as_float(0x7f800000u), me1 = me0, me2 = me0, me3 = me0;
        const float* zp = z + n0 * D_ + d;
        #pragma unroll 8
        for (int i = 0; i < 256; ++i) {
            float zv = zp[i * D_];
            float df;
            df = zv - e0; me0 = fminf(me0, df * df);
            df = zv - e1; me1 = fminf(me1, df * df);
            df = zv - e2; me2 = fminf(me2, df * df);
            df = zv - e3; me3 = fminf(me3, df * df);
        }
        float* pe = ws + (size_t)chunk * (M_ * D_) + m0 * D_ + d;
        pe[0 * D_] = me0;
        pe[1 * D_] = me1;
        pe[2 * D_] = me2;
        pe[3 * D_] = me3;
    } else if (bx < 768) {
        // ---- sum partials: per-(n,m) dsum, per-wave min over n ----
        const int b = bx - 512;
        const int nb = b >> 5, mt = b & 31;
        const int n = nb * 256 + t;
        const int m0 = mt * 16;

        float4 zr[32];
        const float4* z4 = reinterpret_cast<const float4*>(z) + n * 32;
        #pragma unroll
        for (int j = 0; j < 32; ++j) zr[j] = z4[j];

        const float4* e4 = reinterpret_cast<const float4*>(e);
        const int w = t >> 6;
        for (int mi = 0; mi < 16; mi += 2) {
            const int ma = m0 + mi;
            const int mb = ma + 1;
            float a0 = 0.f, a1 = 0.f, a2 = 0.f, a3 = 0.f;
            float b0 = 0.f, b1 = 0.f, b2 = 0.f, b3 = 0.f;
            #pragma unroll
            for (int j = 0; j < 32; ++j) {
                float4 ea = e4[ma * 32 + j];    // wave-uniform
                float4 eb = e4[mb * 32 + j];
                float dx, dy, dz, dw;
                dx = zr[j].x - ea.x; a0 = fmaf(dx, dx, a0);
                dy = zr[j].y - ea.y; a1 = fmaf(dy, dy, a1);
                dz = zr[j].z - ea.z; a2 = fmaf(dz, dz, a2);
                dw = zr[j].w - ea.w; a3 = fmaf(dw, dw, a3);
                dx = zr[j].x - eb.x; b0 = fmaf(dx, dx, b0);
                dy = zr[j].y - eb.y; b1 = fmaf(dy, dy, b1);
                dz = zr[j].z - eb.z; b2 = fmaf(dz, dz, b2);
                dw = zr[j].w - eb.w; b3 = fmaf(dw, dw, b3);
            }
            float sa = (a0 + a1) + (a2 + a3);
            float sb = (b0 + b1) + (b2 + b3);
            #pragma unroll
            for (int off = 32; off; off >>= 1) {
                sa = fminf(sa, __shfl_xor(sa, off));
                sb = fminf(sb, __shfl_xor(sb, off));
            }
            if ((t & 63) == 0) {
                ws[PB_SUM + ma * 32 + nb * 4 + w] = sa;
                ws[PB_SUM + mb * 32 + nb * 4 + w] = sb;
            }
        }
    } else {
        // ---- dropout mask; block 768 zeroes acc/counter ----
        const int b = bx - 768;
        const int i = b * 256 + t;              // float4 index, 65536 total
        const int n = i >> 5;
        const float p = probs[n];
        const float4 zv = reinterpret_cast<const float4*>(z)[i];
        const float4 dv = reinterpret_cast<const float4*>(drop)[i];
        float2 lo, hi;
        lo.x = dv.x < p ? zv.x : 0.f;
        lo.y = dv.y < p ? zv.y : 0.f;
        hi.x = dv.z < p ? zv.z : 0.f;
        hi.y = dv.w < p ? zv.w : 0.f;
        float2* o = reinterpret_cast<float2*>(out + 2) + i * 2;
        o[0] = lo;
        o[1] = hi;
        if (b == 0 && t == 0) {
            ws[ACC_OFF] = 0.f;
            ws[ACC_OFF + 1] = 0.f;
            reinterpret_cast<unsigned int*>(ws)[CNT_OFF] = 0u;
        }
    }
}

__device__ __forceinline__ float min4(float4 v) {
    return fminf(fminf(v.x, v.y), fminf(v.z, v.w));
}

__global__ void __launch_bounds__(256) k_fin(float* __restrict__ ws,
                                             float* __restrict__ out) {
    const int b = blockIdx.x, t = threadIdx.x;
    float* acc = ws + ACC_OFF;
    unsigned int* cnt = reinterpret_cast<unsigned int*>(ws) + CNT_OFF;

    // elem: min over 8 chunks of 4 cells, then local sum
    const int cell = b * 1024 + t * 4;
    float4 mv = *reinterpret_cast<const float4*>(ws + cell);
    #pragma unroll
    for (int c = 1; c < 8; ++c) {
        float4 v = *reinterpret_cast<const float4*>(ws + c * (M_ * D_) + cell);
        mv.x = fminf(mv.x, v.x); mv.y = fminf(mv.y, v.y);
        mv.z = fminf(mv.z, v.z); mv.w = fminf(mv.w, v.w);
    }
    float s_elem = (mv.x + mv.y) + (mv.z + mv.w);

    // sum path: m in [b*8, b*8+8), 8 lanes per m cover 32 partials
    float s_sum = 0.f;
    if (t < 64) {
        const int m = b * 8 + (t >> 3);
        const int j = t & 7;
        float4 v = *reinterpret_cast<const float4*>(ws + PB_SUM + m * 32 + j * 4);
        float mn = min4(v);
        mn = fminf(mn, __shfl_xor(mn, 1));
        mn = fminf(mn, __shfl_xor(mn, 2));
        mn = fminf(mn, __shfl_xor(mn, 4));
        if ((t & 7) == 0) s_sum = mn;
    }

    #pragma unroll
    for (int off = 32; off; off >>= 1) {
        s_elem += __shfl_xor(s_elem, off);
        s_sum  += __shfl_xor(s_sum, off);
    }
    __shared__ float sm[8];
    const int w = t >> 6;
    if ((t & 63) == 0) { sm[w] = s_elem; sm[4 + w] = s_sum; }
    __syncthreads();
    if (t == 0) {
        float te = sm[0] + sm[1] + sm[2] + sm[3];
        float ts = sm[4] + sm[5] + sm[6] + sm[7];
        atomicAdd(&acc[0], ts);
        atomicAdd(&acc[1], te);
        __threadfence();
        unsigned int old = atomicAdd(cnt, 1u);
        if (old == 63u) {
            float a0 = atomicAdd(&acc[0], 0.f);   // RMW read: coherent
            float a1 = atomicAdd(&acc[1], 0.f);
            out[0] = a0 * (1.0f / 512.0f);
            out[1] = a1 * (1.0f / 65536.0f);
        }
    }
}

extern "C" void kernel_launch(void* const* d_in, const int* in_sizes, int n_in,
                              void* d_out, int out_size, void* d_ws, size_t ws_size,
                              hipStream_t stream) {
    const float* z     = (const float*)d_in[0];
    const float* e     = (const float*)d_in[1];
    const float* probs = (const float*)d_in[2];
    const float* drop  = (const float*)d_in[3];
    float* out = (float*)d_out;
    float* ws  = (float*)d_ws;

    k_main<<<dim3(1024), dim3(256), 0, stream>>>(z, e, probs, drop, out, ws);
    k_fin<<<dim3(64), dim3(256), 0, stream>>>(ws, out);
}